// Round 1
// baseline (253.954 us; speedup 1.0000x reference)
//
#include <hip/hip_runtime.h>
#include <stdint.h>

typedef __attribute__((ext_vector_type(8))) short short8;
typedef __attribute__((ext_vector_type(4))) float f32x4;
typedef unsigned short u16;

#define NBATCH 8
#define SLEN 1024
#define CDIM 512
#define NHEADS 8
#define HDIM 64
#define MROWS (NBATCH*SLEN)
#define NQKV (NHEADS*3*HDIM)   // 1536
#define QK_SCALE 0.35355339059327373f  // 64^-0.25

__device__ inline u16 f2bf(float f){
  union{float f; uint32_t i;} v; v.f=f;
  uint32_t r = v.i + 0x7fffu + ((v.i>>16)&1u);
  return (u16)(r>>16);
}

// ---------------- weight prep: cast + transpose to (N, K) bf16 ----------------
__global__ void prep_wqkv(const float* __restrict__ w, u16* __restrict__ wt){
  int idx = blockIdx.x*256 + threadIdx.x;   // over 1536*512
  int n = idx >> 9, k2 = idx & 511;
  wt[idx] = f2bf(w[(size_t)k2*NQKV + n]);
}
__global__ void prep_wout(const float* __restrict__ w, u16* __restrict__ wt){
  int idx = blockIdx.x*256 + threadIdx.x;   // over 512*512
  int n = idx >> 9, k2 = idx & 511;
  wt[idx] = f2bf(w[(size_t)k2*CDIM + n]);
}

// ---------------- groupnorm stats: one block per (b,g) ----------------
__global__ __launch_bounds__(256) void gn_stats(const float* __restrict__ x, float* __restrict__ stats){
  int bid = blockIdx.x;            // b*32+g
  int b = bid >> 5, g = bid & 31;
  int t = threadIdx.x;
  const float* base = x + (size_t)b*SLEN*CDIM + g*16;
  float s1=0.f, s2=0.f;
  for (int s = t; s < SLEN; s += 256){
    const float4* p = (const float4*)(base + (size_t)s*CDIM);
    #pragma unroll
    for (int j=0;j<4;++j){
      float4 v = p[j];
      s1 += v.x+v.y+v.z+v.w;
      s2 += v.x*v.x + v.y*v.y + v.z*v.z + v.w*v.w;
    }
  }
  #pragma unroll
  for (int m=1;m<64;m<<=1){ s1 += __shfl_xor(s1,m); s2 += __shfl_xor(s2,m); }
  __shared__ float red[8];
  int wid = t>>6;
  if ((t&63)==0){ red[wid*2]=s1; red[wid*2+1]=s2; }
  __syncthreads();
  if (t==0){
    float a=0,c=0;
    #pragma unroll
    for (int w2=0;w2<4;++w2){ a+=red[w2*2]; c+=red[w2*2+1]; }
    float mean = a*(1.f/16384.f);
    float var  = c*(1.f/16384.f) - mean*mean;
    stats[bid*2]   = mean;
    stats[bid*2+1] = rsqrtf(var + 1e-5f);
  }
}

// ---------------- normalize + cast to bf16 ----------------
__global__ __launch_bounds__(256) void norm_cast(const float* __restrict__ x, const float* __restrict__ stats,
                        const float* __restrict__ scale, const float* __restrict__ bias,
                        u16* __restrict__ xn){
  int idx = blockIdx.x*256 + threadIdx.x;   // over 8192*32 (one 16-ch group per thread)
  int m = idx >> 5, g = idx & 31;
  int b = m >> 10;
  float mean = stats[(b*32+g)*2];
  float rstd = stats[(b*32+g)*2+1];
  const float* xp = x + (size_t)m*CDIM + g*16;
  const float* sp = scale + g*16;
  const float* bp = bias + g*16;
  short8 o0, o1;
  #pragma unroll
  for (int j=0;j<16;++j){
    float v = (xp[j]-mean)*rstd*sp[j] + bp[j];
    if (j<8) o0[j] = (short)f2bf(v); else o1[j-8] = (short)f2bf(v);
  }
  short8* dst = (short8*)(xn + (size_t)m*CDIM + g*16);
  dst[0]=o0; dst[1]=o1;
}

// ---------------- GEMM: C = A(MxK) * Bt(NxK)^T, bf16 in, fp32 acc ----------------
// EPI=0: QKV epilogue (scatter q,k,vt with scale). EPI=1: out-proj epilogue (+bias+resid, fp32 out)
#define BM 128
#define BN 128
#define BK 64

template<int EPI>
__global__ __launch_bounds__(256) void gemm_bf16(
    const u16* __restrict__ A, const u16* __restrict__ Bt,
    const float* __restrict__ bias, const float* __restrict__ resid,
    float* __restrict__ outF,
    u16* __restrict__ qb, u16* __restrict__ kb, u16* __restrict__ vtb)
{
  const int K = CDIM;
  int t = threadIdx.x;
  int l = t & 63, wid = t >> 6;
  int g = l >> 4, c = l & 15;
  int wr = wid >> 1, wc = wid & 1;
  int m0 = blockIdx.y * BM, n0 = blockIdx.x * BN;

  __shared__ __attribute__((aligned(16))) u16 lsA[BM*BK];
  __shared__ __attribute__((aligned(16))) u16 lsB[BN*BK];
  char* lsAc = (char*)lsA; char* lsBc = (char*)lsB;

  f32x4 acc[4][4];
  #pragma unroll
  for (int i=0;i<4;++i)
    #pragma unroll
    for(int j=0;j<4;++j) acc[i][j] = (f32x4)0.f;

  int srow = t >> 3;      // 0..31
  int ssl  = t & 7;       // 16B slot within 64-col row
  uint4 ra[4], rb[4];
  const int KT = K / BK;  // 8
  #pragma unroll
  for (int i=0;i<4;++i){
    int row = srow + 32*i;
    ra[i] = *(const uint4*)(A  + (size_t)(m0+row)*K + ssl*8);
    rb[i] = *(const uint4*)(Bt + (size_t)(n0+row)*K + ssl*8);
  }
  for (int kt=0; kt<KT; ++kt){
    __syncthreads();
    #pragma unroll
    for (int i=0;i<4;++i){
      int row = srow + 32*i;
      int sw = (ssl ^ (row & 7));
      *(uint4*)(lsAc + row*128 + sw*16) = ra[i];
      *(uint4*)(lsBc + row*128 + sw*16) = rb[i];
    }
    __syncthreads();
    if (kt+1 < KT){
      #pragma unroll
      for (int i=0;i<4;++i){
        int row = srow + 32*i;
        ra[i] = *(const uint4*)(A  + (size_t)(m0+row)*K + (kt+1)*BK + ssl*8);
        rb[i] = *(const uint4*)(Bt + (size_t)(n0+row)*K + (kt+1)*BK + ssl*8);
      }
    }
    #pragma unroll
    for (int kk=0; kk<2; ++kk){
      short8 af[4], bfr[4];
      #pragma unroll
      for (int i=0;i<4;++i){
        int rowA = wr*64 + i*16 + c;
        af[i]  = *(const short8*)(lsAc + rowA*128 + ((kk*4+g) ^ (rowA&7))*16);
        int rowB = wc*64 + i*16 + c;
        bfr[i] = *(const short8*)(lsBc + rowB*128 + ((kk*4+g) ^ (rowB&7))*16);
      }
      #pragma unroll
      for (int i=0;i<4;++i)
        #pragma unroll
        for (int j=0;j<4;++j)
          acc[i][j] = __builtin_amdgcn_mfma_f32_16x16x32_bf16(af[i], bfr[j], acc[i][j], 0,0,0);
    }
  }

  if (EPI == 0){
    int b = m0 >> 10;
    #pragma unroll
    for (int i=0;i<4;++i){
      int grow = m0 + wr*64 + i*16 + g*4;
      #pragma unroll
      for (int j=0;j<4;++j){
        int gcol = n0 + wc*64 + j*16 + c;
        int h = gcol / 192, jj = gcol % 192;
        float bv = bias[gcol];
        #pragma unroll
        for (int r=0;r<4;++r){
          int s = (grow + r) & (SLEN-1);
          float val = acc[i][j][r] + bv;
          if (jj < 64){
            qb[(((size_t)(b*NHEADS+h))*SLEN + s)*HDIM + jj] = f2bf(val*QK_SCALE);
          } else if (jj < 128){
            kb[(((size_t)(b*NHEADS+h))*SLEN + s)*HDIM + (jj-64)] = f2bf(val*QK_SCALE);
          } else {
            vtb[(((size_t)(b*NHEADS+h))*HDIM + (jj-128))*SLEN + s] = f2bf(val);
          }
        }
      }
    }
  } else {
    #pragma unroll
    for (int i=0;i<4;++i){
      int grow = m0 + wr*64 + i*16 + g*4;
      #pragma unroll
      for (int j=0;j<4;++j){
        int gcol = n0 + wc*64 + j*16 + c;
        float bv = bias[gcol];
        #pragma unroll
        for (int r=0;r<4;++r){
          size_t off = (size_t)(grow+r)*CDIM + gcol;
          outF[off] = (acc[i][j][r] + bv + resid[off]);  // SKIP_SCALE == 1.0
        }
      }
    }
  }
}

// ---------------- fused flash attention ----------------
// grid: (B*NH)*16 blocks; block: 256 thr (4 waves), each wave owns 16 q-rows.
__global__ __launch_bounds__(256) void attn_fused(const u16* __restrict__ qg,
  const u16* __restrict__ kg, const u16* __restrict__ vtg, u16* __restrict__ og)
{
  int blk = blockIdx.x;
  int bh = blk >> 4;         // 0..63
  int qt = blk & 15;
  int t = threadIdx.x, l = t&63, wid = t>>6;
  int g = l>>4, c = l&15;
  int qbase = qt*64 + wid*16;

  __shared__ __attribute__((aligned(16))) u16 pbuf[4][16][88];
  char* pb = (char*)&pbuf[wid][0][0];

  const u16* qp = qg + ((size_t)bh*SLEN + qbase)*HDIM;
  short8 aQ[2];
  #pragma unroll
  for (int kk=0;kk<2;++kk)
    aQ[kk] = *(const short8*)(qp + c*HDIM + kk*32 + g*8);

  float m_r[4], l_r[4];
  f32x4 oacc[4];
  #pragma unroll
  for (int r=0;r<4;++r){ m_r[r] = -1e30f; l_r[r]=0.f; }
  #pragma unroll
  for (int d=0;d<4;++d) oacc[d] = (f32x4)0.f;

  const u16* kbase = kg  + (size_t)bh*SLEN*HDIM;
  const u16* vbase = vtg + (size_t)bh*HDIM*SLEN;

  for (int kt=0; kt<16; ++kt){
    f32x4 sc[4];
    #pragma unroll
    for (int s4=0;s4<4;++s4) sc[s4]=(f32x4)0.f;
    const u16* kp = kbase + (size_t)kt*64*HDIM;
    #pragma unroll
    for (int s4=0;s4<4;++s4){
      #pragma unroll
      for (int kk=0;kk<2;++kk){
        short8 bK = *(const short8*)(kp + (size_t)(s4*16+c)*HDIM + kk*32 + g*8);
        sc[s4] = __builtin_amdgcn_mfma_f32_16x16x32_bf16(aQ[kk], bK, sc[s4], 0,0,0);
      }
    }
    // online softmax (rows live in 16-lane groups)
    float tm[4];
    #pragma unroll
    for (int r=0;r<4;++r)
      tm[r] = fmaxf(fmaxf(sc[0][r],sc[1][r]), fmaxf(sc[2][r],sc[3][r]));
    #pragma unroll
    for (int mk=1; mk<16; mk<<=1)
      #pragma unroll
      for (int r=0;r<4;++r) tm[r] = fmaxf(tm[r], __shfl_xor(tm[r], mk));
    float alpha[4], rs[4];
    #pragma unroll
    for (int r=0;r<4;++r){
      float mn = fmaxf(m_r[r], tm[r]);
      alpha[r] = __expf(m_r[r]-mn);
      m_r[r] = mn;
      rs[r]=0.f;
    }
    #pragma unroll
    for (int s4=0;s4<4;++s4)
      #pragma unroll
      for (int r=0;r<4;++r){
        float p = __expf(sc[s4][r]-m_r[r]);
        sc[s4][r]=p; rs[r]+=p;
      }
    #pragma unroll
    for (int mk=1; mk<16; mk<<=1)
      #pragma unroll
      for (int r=0;r<4;++r) rs[r] += __shfl_xor(rs[r], mk);
    #pragma unroll
    for (int r=0;r<4;++r) l_r[r] = l_r[r]*alpha[r] + rs[r];
    #pragma unroll
    for (int d=0;d<4;++d)
      #pragma unroll
      for (int r=0;r<4;++r) oacc[d][r]*=alpha[r];
    // P -> LDS (C/D layout) then re-read as A fragments
    #pragma unroll
    for (int s4=0;s4<4;++s4)
      #pragma unroll
      for (int r=0;r<4;++r)
        pbuf[wid][g*4+r][s4*16+c] = f2bf(sc[s4][r]);
    short8 aP[2];
    #pragma unroll
    for (int kk=0;kk<2;++kk)
      aP[kk] = *(const short8*)(pb + c*176 + kk*64 + g*16);
    const u16* vp = vbase + kt*64;
    #pragma unroll
    for (int d=0; d<4; ++d){
      #pragma unroll
      for (int kk=0;kk<2;++kk){
        short8 bV = *(const short8*)(vp + (size_t)(d*16+c)*SLEN + kk*32 + g*8);
        oacc[d] = __builtin_amdgcn_mfma_f32_16x16x32_bf16(aP[kk], bV, oacc[d], 0,0,0);
      }
    }
  }
  int b = bh >> 3, h = bh & 7;
  #pragma unroll
  for (int r=0;r<4;++r){
    int s = qbase + g*4 + r;
    float inv = 1.f / l_r[r];
    size_t mrow = (size_t)b*SLEN + s;
    #pragma unroll
    for (int d=0;d<4;++d)
      og[mrow*CDIM + h*HDIM + d*16 + c] = f2bf(oacc[d][r]*inv);
  }
}

extern "C" void kernel_launch(void* const* d_in, const int* in_sizes, int n_in,
                              void* d_out, int out_size, void* d_ws, size_t ws_size,
                              hipStream_t stream){
  const float* x      = (const float*)d_in[0];
  const float* nscale = (const float*)d_in[1];
  const float* nbias  = (const float*)d_in[2];
  const float* wqkv   = (const float*)d_in[3];
  const float* bqkv   = (const float*)d_in[4];
  const float* wout   = (const float*)d_in[5];
  const float* bout   = (const float*)d_in[6];
  float* out = (float*)d_out;

  char* ws = (char*)d_ws;
  size_t off = 0;
  auto alloc = [&](size_t bytes){ void* p = ws + off; off += (bytes + 255) & ~255ull; return p; };
  float* stats  = (float*)alloc(256*2*sizeof(float));
  u16* wqkv_t = (u16*)alloc((size_t)NQKV*CDIM*2);
  u16* wout_t = (u16*)alloc((size_t)CDIM*CDIM*2);
  u16* xn     = (u16*)alloc((size_t)MROWS*CDIM*2);
  u16* qb     = (u16*)alloc((size_t)MROWS*CDIM*2);
  u16* kb     = (u16*)alloc((size_t)MROWS*CDIM*2);
  u16* vtb    = (u16*)alloc((size_t)MROWS*CDIM*2);
  u16* ob     = (u16*)alloc((size_t)MROWS*CDIM*2);

  prep_wqkv<<<dim3((NQKV*CDIM)/256), dim3(256), 0, stream>>>(wqkv, wqkv_t);
  prep_wout<<<dim3((CDIM*CDIM)/256), dim3(256), 0, stream>>>(wout, wout_t);
  gn_stats <<<dim3(256), dim3(256), 0, stream>>>(x, stats);
  norm_cast<<<dim3((MROWS*32)/256), dim3(256), 0, stream>>>(x, stats, nscale, nbias, xn);
  gemm_bf16<0><<<dim3(NQKV/BN, MROWS/BM), dim3(256), 0, stream>>>(xn, wqkv_t, bqkv, nullptr, nullptr, qb, kb, vtb);
  attn_fused<<<dim3(64*16), dim3(256), 0, stream>>>(qb, kb, vtb, ob);
  gemm_bf16<1><<<dim3(CDIM/BN, MROWS/BM), dim3(256), 0, stream>>>(ob, wout_t, bout, x, out, nullptr, nullptr, nullptr);
}